// Round 1
// baseline (352.899 us; speedup 1.0000x reference)
//
#include <hip/hip_runtime.h>
#include <stdint.h>

// CodebookLayer (VQ snap): logits = x @ cb^T, argmax over 8192 codes, gather rows.
// R6: port vq_gemm_top3 from the 128x128 2-barrier structure (MfmaUtil 35%, the
// documented m97-class ceiling) to the 256x256 8-phase-style schedule:
//  - 512 threads = 8 waves (2 code-halves x 4 token-quarters), wave tile 128x64,
//    acc[4][2] of 32x32x64 MX-fp8 MFMAs.
//  - 4 LDS buffers (128KB), staged 2 K-tiles ahead via global_load_lds(16B);
//    boundary wait is a counted s_waitcnt vmcnt(4) -- never drained to 0 in the
//    main loop (T4). Raw s_barrier + manual waits, sched_barrier(0) pins.
//  - 2 phases per K-tile, each {ds_read subtile || stage-issue -> barrier ->
//    lgkmcnt(0) -> setprio(1); 4 MFMA; setprio(0) -> barrier} (T3+T5).
//  - Same (row>>1)&3 16B-chunk XOR swizzle (T2): linear GLD dest, pre-swizzled
//    global source, swizzled ds_read -- conflict-free for 32 consecutive rows.
//  - BM=256 => NBLK=32, code-in-block index now 8 bits in the packed key.
// reduce_gather / prep unchanged except NBLK/BM/key-mask adaptation.

#define T_TOKENS 16384
#define N_CODES  8192
#define DIM      1024
#define BM 256                  // codes per block (M = codes)
#define BN 256                  // tokens per block
#define BK 64                   // K bytes staged per tile (fp8)
#define NBLK (N_CODES / BM)     // 32 code chunks
#define KITERS (DIM / BK)       // 16
#define EPS 13.0f
#define MAXCAND 48

typedef int   int8v  __attribute__((ext_vector_type(8)));
typedef int   int4v  __attribute__((ext_vector_type(4)));
typedef float f32x16 __attribute__((ext_vector_type(16)));

// async global->LDS, 16B per lane; LDS dest = wave-uniform base + lane*16
#define GLD16(gp, lp) \
  __builtin_amdgcn_global_load_lds((__attribute__((address_space(1))) void*)(gp), \
                                   (__attribute__((address_space(3))) void*)(lp), 16, 0, 0)

__device__ inline uint32_t umax(uint32_t a, uint32_t b) { return a > b ? a : b; }
__device__ inline uint32_t umin(uint32_t a, uint32_t b) { return a < b ? a : b; }
// compiler pattern-matches to v_med3_u32
__device__ inline uint32_t umed3(uint32_t a, uint32_t b, uint32_t c) {
  return umax(umin(a, b), umin(umax(a, b), c));
}

// monotone f32 -> u32 (larger float => larger uint)
__device__ inline uint32_t f32_key(float v) {
  int32_t b = (int32_t)__float_as_uint(v);
  return (uint32_t)(b ^ ((b >> 31) | (int32_t)0x80000000));
}
__device__ inline float key_f32(uint32_t u) {
  uint32_t b = (u & 0x80000000u) ? (u & 0x7FFFFFFFu) : ~u;
  return __uint_as_float(b);
}

// ------------------------------------------------------------------ prep (fused)
// blocks [0,16384): x (fp32) -> xq (fp8 e4m3); [16384,24576): cb -> cq
__global__ __launch_bounds__(256) void vq_prep(const float* __restrict__ x,
                                               const float* __restrict__ cbm,
                                               uint8_t* __restrict__ xq,
                                               uint8_t* __restrict__ cq) {
  size_t b = blockIdx.x;
  const float* src; uint8_t* dst;
  if (b < 16384) { src = x;  dst = xq; }
  else           { b -= 16384; src = cbm; dst = cq; }
  const size_t i = b * 256 + threadIdx.x;
  const float4 v = ((const float4*)src)[i];
  uint32_t r = __builtin_amdgcn_cvt_pk_fp8_f32(v.x, v.y, 0, false);
  r = __builtin_amdgcn_cvt_pk_fp8_f32(v.z, v.w, (int)r, true);
  ((uint32_t*)dst)[i] = r;
}

// ---------------------------------------------------------------- GEMM + top-3
#define MFMA8(A_, B_, C_) \
  __builtin_amdgcn_mfma_scale_f32_32x32x64_f8f6f4((A_), (B_), (C_), 0, 0, 0, \
                                                  0x7F7F7F7F, 0, 0x7F7F7F7F)

__global__ __launch_bounds__(512) void vq_gemm_top3(
    const uint8_t* __restrict__ cq,   // [C][D] fp8 (A operand)
    const uint8_t* __restrict__ xq,   // [T][D] fp8 (B operand)
    uint32_t* __restrict__ pk)        // [T][NBLK][3] packed keys
{
  // 4 staging buffers of 32KB: A(16KB) | B(16KB) each. Total 128KB.
  __shared__ uint8_t smem[4 * 32768];

  const int t    = threadIdx.x;
  const int wave = t >> 6;
  const int lane = t & 63;
  const int col  = lane & 31;
  const int hi   = lane >> 5;
  const int wm   = wave >> 2;          // 0..1: code half (128 codes)
  const int wn2  = (wave & 3) * 64;    // token offset within block

  // XCD-bijective swizzle over 2048 wgs (nwg%8==0): each XCD gets 4 code panels
  // x all 64 token panels -> cq panels stay L2-resident.
  const int f   = blockIdx.x;
  const int swz = (f & 7) * 256 + (f >> 3);
  const int cyi = swz >> 6;            // code chunk 0..31
  const int tb0 = (swz & 63) * BN;
  const int cb0 = cyi * BM;

  // Staging: per buffer 2048 chunks of 16B (A 1024 | B 1024). Thread handles
  // chunks {t, t+512} of each. Dest is LINEAR (chunk c -> byte c*16); the
  // source k-chunk is pre-swizzled: row r stores source chunk j^((r>>1)&3) at
  // slot j. Note rows r and r+128 share the same swizzle ((r>>1)&3 invariant
  // under +128), so one source k-offset js serves both chunks.
  const int r0 = t >> 2;                                   // 0..127
  const int js = ((t & 3) ^ ((r0 >> 1) & 3)) * 16;
  const uint8_t* sA0 = cq + (size_t)(cb0 + r0) * DIM + js;
  const uint8_t* sA1 = cq + (size_t)(cb0 + r0 + 128) * DIM + js;
  const uint8_t* sB0 = xq + (size_t)(tb0 + r0) * DIM + js;
  const uint8_t* sB1 = xq + (size_t)(tb0 + r0 + 128) * DIM + js;

#define STAGE(bi, ti) do {                                     \
    uint8_t* Ad_ = smem + ((bi) << 15);                        \
    const int ko_ = (ti) * BK;                                 \
    GLD16(sA0 + ko_, Ad_ + t * 16);                            \
    GLD16(sA1 + ko_, Ad_ + (t + 512) * 16);                    \
    GLD16(sB0 + ko_, Ad_ + 16384 + t * 16);                    \
    GLD16(sB1 + ko_, Ad_ + 16384 + (t + 512) * 16);            \
  } while (0)

  // ds_read offsets: fragment = row, source k-chunks {2*hi, 2*hi+1} -> slots
  // XOR'd with perm(row). Precomputed as byte offsets into a buffer.
  const int j0 = hi * 2;
  int aoff[4][2], boff[2][2];
#pragma unroll
  for (int mi = 0; mi < 4; ++mi) {
    const int ra = wm * 128 + mi * 32 + col;
    const int pa = (ra >> 1) & 3;
    aoff[mi][0] = ra * 64 + (j0 ^ pa) * 16;
    aoff[mi][1] = ra * 64 + ((j0 + 1) ^ pa) * 16;
  }
#pragma unroll
  for (int jj = 0; jj < 2; ++jj) {
    const int rb = wn2 + jj * 32 + col;
    const int pb = (rb >> 1) & 3;
    boff[jj][0] = 16384 + rb * 64 + (j0 ^ pb) * 16;
    boff[jj][1] = 16384 + rb * 64 + ((j0 + 1) ^ pb) * 16;
  }

#define READ8(dst_, o0_, o1_) do {                                         \
    const int4v lo_ = *(const int4v*)(cur + (o0_));                        \
    const int4v hq_ = *(const int4v*)(cur + (o1_));                        \
    dst_ = (int8v){lo_[0], lo_[1], lo_[2], lo_[3],                         \
                   hq_[0], hq_[1], hq_[2], hq_[3]};                        \
  } while (0)

  f32x16 acc[4][2];
#pragma unroll
  for (int i = 0; i < 4; ++i)
#pragma unroll
    for (int j = 0; j < 2; ++j)
#pragma unroll
      for (int r = 0; r < 16; ++r) acc[i][j][r] = 0.f;

  // prologue: tiles 0,1 in flight (8 vmem ops/thread)
  STAGE(0, 0);
  STAGE(1, 1);

#pragma unroll 4
  for (int kt = 0; kt < KITERS; ++kt) {
    // tile boundary: counted wait -- newest 4 (tile kt+1's stage) stay in
    // flight; everything older (incl. tile kt) has landed. Barrier makes it
    // workgroup-wide; sched_barrier pins ds_reads below it.
    asm volatile("s_waitcnt vmcnt(4)" ::: "memory");
    __builtin_amdgcn_s_barrier();
    __builtin_amdgcn_sched_barrier(0);

    const uint8_t* cur = smem + ((kt & 3) << 15);
    // stage tile kt+2 two tiles ahead. (kt+2)&15 wraps: the last two stages
    // re-read tiles 0/1 into buffers 0/1 (never read again, keeps the vmcnt
    // accounting uniform, no OOB).
    STAGE((kt + 2) & 3, (kt + 2) & 15);

    // ---- phase 0: read A0..A3 + B0, MFMA column 0
    int8v a[4], b0, b1;
#pragma unroll
    for (int mi = 0; mi < 4; ++mi) READ8(a[mi], aoff[mi][0], aoff[mi][1]);
    READ8(b0, boff[0][0], boff[0][1]);
    __builtin_amdgcn_s_barrier();
    asm volatile("s_waitcnt lgkmcnt(0)" ::: "memory");
    __builtin_amdgcn_sched_barrier(0);
    __builtin_amdgcn_s_setprio(1);
    acc[0][0] = MFMA8(a[0], b0, acc[0][0]);
    acc[1][0] = MFMA8(a[1], b0, acc[1][0]);
    acc[2][0] = MFMA8(a[2], b0, acc[2][0]);
    acc[3][0] = MFMA8(a[3], b0, acc[3][0]);
    __builtin_amdgcn_s_setprio(0);
    __builtin_amdgcn_s_barrier();

    // ---- phase 1: read B1, MFMA column 1 (A frags still live)
    READ8(b1, boff[1][0], boff[1][1]);
    __builtin_amdgcn_s_barrier();
    asm volatile("s_waitcnt lgkmcnt(0)" ::: "memory");
    __builtin_amdgcn_sched_barrier(0);
    __builtin_amdgcn_s_setprio(1);
    acc[0][1] = MFMA8(a[0], b1, acc[0][1]);
    acc[1][1] = MFMA8(a[1], b1, acc[1][1]);
    acc[2][1] = MFMA8(a[2], b1, acc[2][1]);
    acc[3][1] = MFMA8(a[3], b1, acc[3][1]);
    __builtin_amdgcn_s_setprio(0);
    // next iteration's vmcnt+barrier closes the tile
  }
  __syncthreads();   // full drain before smem reuse

  // Epilogue: per-token top-3 over this block's 256 codes.
  // C/D 32x32 layout: col(token)=lane&31, row(code)=(reg&3)+8*(reg>>2)+4*(lane>>5).
  // key = (monotone(value) & ~0xFF) | (255 - code_in_block).
  // cand lives in buffer 2 (buffers 0/1 may still be targets of the redundant
  // wrap stages -- __syncthreads drained them, but keep clear anyway).
  uint32_t* cand = (uint32_t*)(smem + 2 * 32768);  // [256 tokens][2 halves][3]
  const int invb = 255 - wm * 128 - 4 * hi;
#pragma unroll
  for (int j = 0; j < 2; ++j) {
    uint32_t K1 = 0, K2 = 0, K3 = 0;
#pragma unroll
    for (int mi = 0; mi < 4; ++mi) {
#pragma unroll
      for (int rg = 0; rg < 16; ++rg) {
        const int rowoff = (rg & 3) + 8 * (rg >> 2);
        const uint32_t key = (f32_key(acc[mi][j][rg]) & 0xFFFFFF00u)
                           | (uint32_t)(invb - mi * 32 - rowoff);
        const uint32_t t3 = umed3(key, K2, K3);
        const uint32_t t2 = umed3(key, K1, K2);
        K1 = umax(key, K1); K2 = t2; K3 = t3;
      }
    }
    // merge row-halves (lane ^ 32 holds same token, other 4-row offset)
    const uint32_t o1 = __shfl_xor(K1, 32, 64);
    const uint32_t o2 = __shfl_xor(K2, 32, 64);
    const uint32_t o3 = __shfl_xor(K3, 32, 64);
    const uint32_t m1 = umin(K1, o1), M2 = umax(K2, o2);
    const uint32_t m2 = umin(K2, o2), M3 = umax(K3, o3);
    K1 = umax(K1, o1);
    const uint32_t nk2 = umax(m1, M2);
    K3 = umax(umax(m2, umin(m1, M2)), M3);
    K2 = nk2;
    if (hi == 0) {
      uint32_t* c = &cand[((wn2 + j * 32 + col) * 2 + wm) * 3];
      c[0] = K1; c[1] = K2; c[2] = K3;
    }
  }
  __syncthreads();
  if (t < BN) {
    const uint32_t a1 = cand[(t * 2 + 0) * 3 + 0], a2 = cand[(t * 2 + 0) * 3 + 1],
                   a3 = cand[(t * 2 + 0) * 3 + 2];
    const uint32_t b1k = cand[(t * 2 + 1) * 3 + 0], b2 = cand[(t * 2 + 1) * 3 + 1],
                   b3 = cand[(t * 2 + 1) * 3 + 2];
    const uint32_t m1 = umin(a1, b1k), M2 = umax(a2, b2);
    const uint32_t m2 = umin(a2, b2), M3 = umax(a3, b3);
    uint32_t* dst = pk + ((size_t)(tb0 + t) * NBLK + cyi) * 3;
    dst[0] = umax(a1, b1k);
    dst[1] = umax(m1, M2);
    dst[2] = umax(umax(m2, umin(m1, M2)), M3);
  }
#undef STAGE
#undef READ8
}

// ------------------------------------------- reduce + fp64 recheck + gather
__global__ __launch_bounds__(256) void vq_reduce_gather(
    const uint32_t* __restrict__ pk, const float* __restrict__ x,
    const float* __restrict__ cb, float* __restrict__ out)
{
  __shared__ float xs[DIM];
  __shared__ uint32_t wmax[4];
  __shared__ int scand[MAXCAND];
  __shared__ int scnt;
  __shared__ double sdot[MAXCAND];
  __shared__ int sbesti;

  const int tkn = blockIdx.x, t = threadIdx.x, lane = t & 63, wv = t >> 6;
  ((float4*)xs)[t] = ((const float4*)(x + (size_t)tkn * DIM))[t];
  const uint32_t key = (t < 3 * NBLK) ? pk[(size_t)tkn * (3 * NBLK) + t] : 0u;
  uint32_t m = key;
#pragma unroll
  for (int d = 1; d < 64; d <<= 1) m = umax(m, __shfl_xor(m, d, 64));
  if (t == 0) scnt = 0;
  if (lane == 0) wmax[wv] = m;
  __syncthreads();
  const float Mv = key_f32(umax(umax(wmax[0], wmax[1]), umax(wmax[2], wmax[3])));
  if (t < 3 * NBLK && key_f32(key) >= Mv - EPS) {
    const int p = atomicAdd(&scnt, 1);
    if (p < MAXCAND) scand[p] = (t / 3) * BM + 255 - (int)(key & 255u);
  }
  __syncthreads();
  const int cnt = scnt < MAXCAND ? scnt : MAXCAND;

  if (cnt > 1) {
    // wave-parallel: wave wv handles candidates wv, wv+4, ...
    for (int k = wv; k < cnt; k += 4) {
      const int c = scand[k];
      const float* cr = cb + (size_t)c * DIM;
      double s = 0.0;
#pragma unroll
      for (int q = 0; q < 4; ++q) {
        const float4 xv = ((const float4*)xs)[lane + 64 * q];
        const float4 cv = ((const float4*)cr)[lane + 64 * q];
        s += (double)xv.x * cv.x + (double)xv.y * cv.y
           + (double)xv.z * cv.z + (double)xv.w * cv.w;
      }
#pragma unroll
      for (int d = 1; d < 64; d <<= 1) s += __shfl_xor(s, d, 64);
      if (lane == 0) sdot[k] = s;
    }
    __syncthreads();
    if (t == 0) {
      double best = -1e300; int bi = N_CODES;
      for (int k = 0; k < cnt; ++k) {
        const int c = scand[k];
        if (sdot[k] > best || (sdot[k] == best && c < bi)) { best = sdot[k]; bi = c; }
      }
      sbesti = bi;
    }
  } else {
    if (t == 0) sbesti = scand[0];
  }
  __syncthreads();
  const int code = sbesti;
  ((float4*)(out + (size_t)tkn * DIM))[t] = ((const float4*)(cb + (size_t)code * DIM))[t];
}

// ------------------------------------------------- fallback (ws too small)
__global__ __launch_bounds__(256) void vq_naive(const float* __restrict__ x,
                                                const float* __restrict__ cb,
                                                float* __restrict__ out) {
  __shared__ float xs[DIM];
  __shared__ float bv[256];
  __shared__ int   bix[256];
  const int tkn = blockIdx.x;
  const int t = threadIdx.x;
  for (int d = t; d < DIM; d += 256) xs[d] = x[(size_t)tkn * DIM + d];
  __syncthreads();
  float best = -1e30f; int bi = N_CODES;
  for (int c = t; c < N_CODES; c += 256) {
    const float* cr = cb + (size_t)c * DIM;
    float s = 0.f;
    for (int d = 0; d < DIM; ++d) s += xs[d] * cr[d];
    if (s > best || (s == best && c < bi)) { best = s; bi = c; }
  }
  bv[t] = best; bix[t] = bi;
  __syncthreads();
  for (int off = 128; off > 0; off >>= 1) {
    if (t < off) {
      if (bv[t + off] > bv[t] || (bv[t + off] == bv[t] && bix[t + off] < bix[t])) {
        bv[t] = bv[t + off]; bix[t] = bix[t + off];
      }
    }
    __syncthreads();
  }
  const int code = bix[0];
  for (int d = t; d < DIM; d += 256)
    out[(size_t)tkn * DIM + d] = cb[(size_t)code * DIM + d];
}

// ---------------------------------------------------------------------- launch
extern "C" void kernel_launch(void* const* d_in, const int* in_sizes, int n_in,
                              void* d_out, int out_size, void* d_ws, size_t ws_size,
                              hipStream_t stream) {
  const float* x  = (const float*)d_in[0];   // [16384][1024]
  const float* cb = (const float*)d_in[1];   // [8192][1024]
  float* out = (float*)d_out;

  const size_t MB = 1024 * 1024;
  const size_t need = 24 * MB + (size_t)T_TOKENS * NBLK * 3 * 4;  // ~30.3MB
  if (ws_size >= need) {
    uint8_t*  xq = (uint8_t*)d_ws;             // 16MB fp8 tokens
    uint8_t*  cq = xq + 16 * MB;               // 8MB  fp8 codebook
    uint32_t* pk = (uint32_t*)(cq + 8 * MB);   // 6.3MB packed keys

    vq_prep<<<dim3(24576), 256, 0, stream>>>(x, cb, xq, cq);
    vq_gemm_top3<<<dim3((T_TOKENS / BN) * (N_CODES / BM)), 512, 0, stream>>>(cq, xq, pk);
    vq_reduce_gather<<<dim3(T_TOKENS), 256, 0, stream>>>(pk, x, cb, out);
  } else {
    vq_naive<<<dim3(T_TOKENS), 256, 0, stream>>>(x, cb, out);
  }
}

// Round 2
// 322.186 us; speedup vs baseline: 1.0953x; 1.0953x over previous
//
#include <hip/hip_runtime.h>
#include <stdint.h>

// CodebookLayer (VQ snap): logits = x @ cb^T, argmax over 8192 codes, gather rows.
// R7: R6's phase-lockstep serialized the LDS pipe against the matrix pipe
// (per-tile: MFMA 1100 cyc, LDS reads ~1550 cyc, measured tile 3170 cyc ==
// serial sum; MfmaUtil pinned at 35% = 1100/3170). With MX-fp8 the MFMA rate
// is 2x bf16, so LDS-read time ~= MFMA time and the m201-style barriers cost
// ~2x. Fix: keep counted-vmcnt tile boundary (never drain to 0), ONE barrier
// per tile, and let the compiler interleave ds_read/MFMA (documented to emit
// fine-grained partial lgkmcnt) so the 2 waves/SIMD drift and overlap
// LDS-reads with MFMAs. Fragments via __builtin_shufflevector (concat) to
// avoid int8v element-insert v_movs.

#define T_TOKENS 16384
#define N_CODES  8192
#define DIM      1024
#define BM 256                  // codes per block (M = codes)
#define BN 256                  // tokens per block
#define BK 64                   // K bytes staged per tile (fp8)
#define NBLK (N_CODES / BM)     // 32 code chunks
#define KITERS (DIM / BK)       // 16
#define EPS 13.0f
#define MAXCAND 48

typedef int   int8v  __attribute__((ext_vector_type(8)));
typedef int   int4v  __attribute__((ext_vector_type(4)));
typedef float f32x16 __attribute__((ext_vector_type(16)));

// async global->LDS, 16B per lane; LDS dest = wave-uniform base + lane*16
#define GLD16(gp, lp) \
  __builtin_amdgcn_global_load_lds((__attribute__((address_space(1))) void*)(gp), \
                                   (__attribute__((address_space(3))) void*)(lp), 16, 0, 0)

__device__ inline uint32_t umax(uint32_t a, uint32_t b) { return a > b ? a : b; }
__device__ inline uint32_t umin(uint32_t a, uint32_t b) { return a < b ? a : b; }
// compiler pattern-matches to v_med3_u32
__device__ inline uint32_t umed3(uint32_t a, uint32_t b, uint32_t c) {
  return umax(umin(a, b), umin(umax(a, b), c));
}

// monotone f32 -> u32 (larger float => larger uint)
__device__ inline uint32_t f32_key(float v) {
  int32_t b = (int32_t)__float_as_uint(v);
  return (uint32_t)(b ^ ((b >> 31) | (int32_t)0x80000000));
}
__device__ inline float key_f32(uint32_t u) {
  uint32_t b = (u & 0x80000000u) ? (u & 0x7FFFFFFFu) : ~u;
  return __uint_as_float(b);
}

// ------------------------------------------------------------------ prep (fused)
// blocks [0,16384): x (fp32) -> xq (fp8 e4m3); [16384,24576): cb -> cq
__global__ __launch_bounds__(256) void vq_prep(const float* __restrict__ x,
                                               const float* __restrict__ cbm,
                                               uint8_t* __restrict__ xq,
                                               uint8_t* __restrict__ cq) {
  size_t b = blockIdx.x;
  const float* src; uint8_t* dst;
  if (b < 16384) { src = x;  dst = xq; }
  else           { b -= 16384; src = cbm; dst = cq; }
  const size_t i = b * 256 + threadIdx.x;
  const float4 v = ((const float4*)src)[i];
  uint32_t r = __builtin_amdgcn_cvt_pk_fp8_f32(v.x, v.y, 0, false);
  r = __builtin_amdgcn_cvt_pk_fp8_f32(v.z, v.w, (int)r, true);
  ((uint32_t*)dst)[i] = r;
}

// ---------------------------------------------------------------- GEMM + top-3
#define MFMA8(A_, B_, C_) \
  __builtin_amdgcn_mfma_scale_f32_32x32x64_f8f6f4((A_), (B_), (C_), 0, 0, 0, \
                                                  0x7F7F7F7F, 0, 0x7F7F7F7F)

__global__ __launch_bounds__(512) void vq_gemm_top3(
    const uint8_t* __restrict__ cq,   // [C][D] fp8 (A operand)
    const uint8_t* __restrict__ xq,   // [T][D] fp8 (B operand)
    uint32_t* __restrict__ pk)        // [T][NBLK][3] packed keys
{
  // 4 staging buffers of 32KB: A(16KB) | B(16KB) each. Total 128KB.
  __shared__ uint8_t smem[4 * 32768];

  const int t    = threadIdx.x;
  const int wave = t >> 6;
  const int lane = t & 63;
  const int col  = lane & 31;
  const int hi   = lane >> 5;
  const int wm   = wave >> 2;          // 0..1: code half (128 codes)
  const int wn2  = (wave & 3) * 64;    // token offset within block

  // XCD-bijective swizzle over 2048 wgs (nwg%8==0): each XCD gets 4 code panels
  // x all 64 token panels -> cq panels stay L2-resident.
  const int f   = blockIdx.x;
  const int swz = (f & 7) * 256 + (f >> 3);
  const int cyi = swz >> 6;            // code chunk 0..31
  const int tb0 = (swz & 63) * BN;
  const int cb0 = cyi * BM;

  // Staging: per buffer 2048 chunks of 16B (A 1024 | B 1024). Thread handles
  // chunks {t, t+512} of each. Dest is LINEAR (chunk c -> byte c*16); the
  // source k-chunk is pre-swizzled: row r stores source chunk j^((r>>1)&3) at
  // slot j. Rows r and r+128 share the same swizzle.
  const int r0 = t >> 2;                                   // 0..127
  const int js = ((t & 3) ^ ((r0 >> 1) & 3)) * 16;
  const uint8_t* sA0 = cq + (size_t)(cb0 + r0) * DIM + js;
  const uint8_t* sA1 = cq + (size_t)(cb0 + r0 + 128) * DIM + js;
  const uint8_t* sB0 = xq + (size_t)(tb0 + r0) * DIM + js;
  const uint8_t* sB1 = xq + (size_t)(tb0 + r0 + 128) * DIM + js;

#define STAGE(bi, ti) do {                                     \
    uint8_t* Ad_ = smem + ((bi) << 15);                        \
    const int ko_ = (ti) * BK;                                 \
    GLD16(sA0 + ko_, Ad_ + t * 16);                            \
    GLD16(sA1 + ko_, Ad_ + (t + 512) * 16);                    \
    GLD16(sB0 + ko_, Ad_ + 16384 + t * 16);                    \
    GLD16(sB1 + ko_, Ad_ + 16384 + (t + 512) * 16);            \
  } while (0)

  // ds_read offsets: fragment = row, source k-chunks {2*hi, 2*hi+1} -> slots
  // XOR'd with perm(row). Precomputed as byte offsets into a buffer.
  const int j0 = hi * 2;
  int aoff[4][2], boff[2][2];
#pragma unroll
  for (int mi = 0; mi < 4; ++mi) {
    const int ra = wm * 128 + mi * 32 + col;
    const int pa = (ra >> 1) & 3;
    aoff[mi][0] = ra * 64 + (j0 ^ pa) * 16;
    aoff[mi][1] = ra * 64 + ((j0 + 1) ^ pa) * 16;
  }
#pragma unroll
  for (int jj = 0; jj < 2; ++jj) {
    const int rb = wn2 + jj * 32 + col;
    const int pb = (rb >> 1) & 3;
    boff[jj][0] = 16384 + rb * 64 + (j0 ^ pb) * 16;
    boff[jj][1] = 16384 + rb * 64 + ((j0 + 1) ^ pb) * 16;
  }

  // concat two b128 loads into one 32B fragment (no element-insert movs)
#define READ8(dst_, o0_, o1_) do {                                         \
    const int4v lo_ = *(const int4v*)(cur + (o0_));                        \
    const int4v hq_ = *(const int4v*)(cur + (o1_));                        \
    dst_ = __builtin_shufflevector(lo_, hq_, 0, 1, 2, 3, 4, 5, 6, 7);      \
  } while (0)

  f32x16 acc[4][2];
#pragma unroll
  for (int i = 0; i < 4; ++i)
#pragma unroll
    for (int j = 0; j < 2; ++j)
#pragma unroll
      for (int r = 0; r < 16; ++r) acc[i][j][r] = 0.f;

  // prologue: tiles 0,1 in flight (8 vmem ops/thread)
  STAGE(0, 0);
  STAGE(1, 1);

#pragma unroll 4
  for (int kt = 0; kt < KITERS; ++kt) {
    // tile boundary: counted wait -- newest 4 (tile kt+1's stage) stay in
    // flight; everything older (incl. tile kt) has landed. ONE barrier per
    // tile; buffer rotation distance 2 makes this sufficient.
    asm volatile("s_waitcnt vmcnt(4)" ::: "memory");
    __builtin_amdgcn_s_barrier();
    __builtin_amdgcn_sched_barrier(0);

    const uint8_t* cur = smem + ((kt & 3) << 15);
    // stage tile kt+2 two tiles ahead. (kt+2)&15 wraps: the last two stages
    // re-read tiles 0/1 into buffers 0/1 (never read again; keeps the vmcnt
    // accounting uniform, no OOB).
    STAGE((kt + 2) & 3, (kt + 2) & 15);

    // whole tile: 12 ds_read_b128 + 8 MFMA, compiler-scheduled. The compiler
    // emits partial lgkmcnt waits so MFMAs start as fragments land; the two
    // waves per SIMD drift within the tile window, overlapping one wave's
    // LDS reads with the other's MFMAs.
    int8v a[4], b[2];
#pragma unroll
    for (int mi = 0; mi < 4; ++mi) READ8(a[mi], aoff[mi][0], aoff[mi][1]);
#pragma unroll
    for (int jj = 0; jj < 2; ++jj) READ8(b[jj], boff[jj][0], boff[jj][1]);

    acc[0][0] = MFMA8(a[0], b[0], acc[0][0]);
    acc[1][0] = MFMA8(a[1], b[0], acc[1][0]);
    acc[0][1] = MFMA8(a[0], b[1], acc[0][1]);
    acc[1][1] = MFMA8(a[1], b[1], acc[1][1]);
    acc[2][0] = MFMA8(a[2], b[0], acc[2][0]);
    acc[3][0] = MFMA8(a[3], b[0], acc[3][0]);
    acc[2][1] = MFMA8(a[2], b[1], acc[2][1]);
    acc[3][1] = MFMA8(a[3], b[1], acc[3][1]);
  }
  __syncthreads();   // full drain before smem reuse

  // Epilogue: per-token top-3 over this block's 256 codes.
  // C/D 32x32 layout: col(token)=lane&31, row(code)=(reg&3)+8*(reg>>2)+4*(lane>>5).
  // key = (monotone(value) & ~0xFF) | (255 - code_in_block).
  uint32_t* cand = (uint32_t*)(smem + 2 * 32768);  // [256 tokens][2 halves][3]
  const int invb = 255 - wm * 128 - 4 * hi;
#pragma unroll
  for (int j = 0; j < 2; ++j) {
    uint32_t K1 = 0, K2 = 0, K3 = 0;
#pragma unroll
    for (int mi = 0; mi < 4; ++mi) {
#pragma unroll
      for (int rg = 0; rg < 16; ++rg) {
        const int rowoff = (rg & 3) + 8 * (rg >> 2);
        const uint32_t key = (f32_key(acc[mi][j][rg]) & 0xFFFFFF00u)
                           | (uint32_t)(invb - mi * 32 - rowoff);
        const uint32_t t3 = umed3(key, K2, K3);
        const uint32_t t2 = umed3(key, K1, K2);
        K1 = umax(key, K1); K2 = t2; K3 = t3;
      }
    }
    // merge row-halves (lane ^ 32 holds same token, other 4-row offset)
    const uint32_t o1 = __shfl_xor(K1, 32, 64);
    const uint32_t o2 = __shfl_xor(K2, 32, 64);
    const uint32_t o3 = __shfl_xor(K3, 32, 64);
    const uint32_t m1 = umin(K1, o1), M2 = umax(K2, o2);
    const uint32_t m2 = umin(K2, o2), M3 = umax(K3, o3);
    K1 = umax(K1, o1);
    const uint32_t nk2 = umax(m1, M2);
    K3 = umax(umax(m2, umin(m1, M2)), M3);
    K2 = nk2;
    if (hi == 0) {
      uint32_t* c = &cand[((wn2 + j * 32 + col) * 2 + wm) * 3];
      c[0] = K1; c[1] = K2; c[2] = K3;
    }
  }
  __syncthreads();
  if (t < BN) {
    const uint32_t a1 = cand[(t * 2 + 0) * 3 + 0], a2 = cand[(t * 2 + 0) * 3 + 1],
                   a3 = cand[(t * 2 + 0) * 3 + 2];
    const uint32_t b1k = cand[(t * 2 + 1) * 3 + 0], b2 = cand[(t * 2 + 1) * 3 + 1],
                   b3 = cand[(t * 2 + 1) * 3 + 2];
    const uint32_t m1 = umin(a1, b1k), M2 = umax(a2, b2);
    const uint32_t m2 = umin(a2, b2), M3 = umax(a3, b3);
    uint32_t* dst = pk + ((size_t)(tb0 + t) * NBLK + cyi) * 3;
    dst[0] = umax(a1, b1k);
    dst[1] = umax(m1, M2);
    dst[2] = umax(umax(m2, umin(m1, M2)), M3);
  }
#undef STAGE
#undef READ8
}

// ------------------------------------------- reduce + fp64 recheck + gather
__global__ __launch_bounds__(256) void vq_reduce_gather(
    const uint32_t* __restrict__ pk, const float* __restrict__ x,
    const float* __restrict__ cb, float* __restrict__ out)
{
  __shared__ float xs[DIM];
  __shared__ uint32_t wmax[4];
  __shared__ int scand[MAXCAND];
  __shared__ int scnt;
  __shared__ double sdot[MAXCAND];
  __shared__ int sbesti;

  const int tkn = blockIdx.x, t = threadIdx.x, lane = t & 63, wv = t >> 6;
  ((float4*)xs)[t] = ((const float4*)(x + (size_t)tkn * DIM))[t];
  const uint32_t key = (t < 3 * NBLK) ? pk[(size_t)tkn * (3 * NBLK) + t] : 0u;
  uint32_t m = key;
#pragma unroll
  for (int d = 1; d < 64; d <<= 1) m = umax(m, __shfl_xor(m, d, 64));
  if (t == 0) scnt = 0;
  if (lane == 0) wmax[wv] = m;
  __syncthreads();
  const float Mv = key_f32(umax(umax(wmax[0], wmax[1]), umax(wmax[2], wmax[3])));
  if (t < 3 * NBLK && key_f32(key) >= Mv - EPS) {
    const int p = atomicAdd(&scnt, 1);
    if (p < MAXCAND) scand[p] = (t / 3) * BM + 255 - (int)(key & 255u);
  }
  __syncthreads();
  const int cnt = scnt < MAXCAND ? scnt : MAXCAND;

  if (cnt > 1) {
    // wave-parallel: wave wv handles candidates wv, wv+4, ...
    for (int k = wv; k < cnt; k += 4) {
      const int c = scand[k];
      const float* cr = cb + (size_t)c * DIM;
      double s = 0.0;
#pragma unroll
      for (int q = 0; q < 4; ++q) {
        const float4 xv = ((const float4*)xs)[lane + 64 * q];
        const float4 cv = ((const float4*)cr)[lane + 64 * q];
        s += (double)xv.x * cv.x + (double)xv.y * cv.y
           + (double)xv.z * cv.z + (double)xv.w * cv.w;
      }
#pragma unroll
      for (int d = 1; d < 64; d <<= 1) s += __shfl_xor(s, d, 64);
      if (lane == 0) sdot[k] = s;
    }
    __syncthreads();
    if (t == 0) {
      double best = -1e300; int bi = N_CODES;
      for (int k = 0; k < cnt; ++k) {
        const int c = scand[k];
        if (sdot[k] > best || (sdot[k] == best && c < bi)) { best = sdot[k]; bi = c; }
      }
      sbesti = bi;
    }
  } else {
    if (t == 0) sbesti = scand[0];
  }
  __syncthreads();
  const int code = sbesti;
  ((float4*)(out + (size_t)tkn * DIM))[t] = ((const float4*)(cb + (size_t)code * DIM))[t];
}

// ------------------------------------------------- fallback (ws too small)
__global__ __launch_bounds__(256) void vq_naive(const float* __restrict__ x,
                                                const float* __restrict__ cb,
                                                float* __restrict__ out) {
  __shared__ float xs[DIM];
  __shared__ float bv[256];
  __shared__ int   bix[256];
  const int tkn = blockIdx.x;
  const int t = threadIdx.x;
  for (int d = t; d < DIM; d += 256) xs[d] = x[(size_t)tkn * DIM + d];
  __syncthreads();
  float best = -1e30f; int bi = N_CODES;
  for (int c = t; c < N_CODES; c += 256) {
    const float* cr = cb + (size_t)c * DIM;
    float s = 0.f;
    for (int d = 0; d < DIM; ++d) s += xs[d] * cr[d];
    if (s > best || (s == best && c < bi)) { best = s; bi = c; }
  }
  bv[t] = best; bix[t] = bi;
  __syncthreads();
  for (int off = 128; off > 0; off >>= 1) {
    if (t < off) {
      if (bv[t + off] > bv[t] || (bv[t + off] == bv[t] && bix[t + off] < bix[t])) {
        bv[t] = bv[t + off]; bix[t] = bix[t + off];
      }
    }
    __syncthreads();
  }
  const int code = bix[0];
  for (int d = t; d < DIM; d += 256)
    out[(size_t)tkn * DIM + d] = cb[(size_t)code * DIM + d];
}

// ---------------------------------------------------------------------- launch
extern "C" void kernel_launch(void* const* d_in, const int* in_sizes, int n_in,
                              void* d_out, int out_size, void* d_ws, size_t ws_size,
                              hipStream_t stream) {
  const float* x  = (const float*)d_in[0];   // [16384][1024]
  const float* cb = (const float*)d_in[1];   // [8192][1024]
  float* out = (float*)d_out;

  const size_t MB = 1024 * 1024;
  const size_t need = 24 * MB + (size_t)T_TOKENS * NBLK * 3 * 4;  // ~30.3MB
  if (ws_size >= need) {
    uint8_t*  xq = (uint8_t*)d_ws;             // 16MB fp8 tokens
    uint8_t*  cq = xq + 16 * MB;               // 8MB  fp8 codebook
    uint32_t* pk = (uint32_t*)(cq + 8 * MB);   // 6.3MB packed keys

    vq_prep<<<dim3(24576), 256, 0, stream>>>(x, cb, xq, cq);
    vq_gemm_top3<<<dim3((T_TOKENS / BN) * (N_CODES / BM)), 512, 0, stream>>>(cq, xq, pk);
    vq_reduce_gather<<<dim3(T_TOKENS), 256, 0, stream>>>(pk, x, cb, out);
  } else {
    vq_naive<<<dim3(T_TOKENS), 256, 0, stream>>>(x, cb, out);
  }
}